// Round 9
// baseline (304.441 us; speedup 1.0000x reference)
//
#include <hip/hip_runtime.h>
#include <math.h>

#define VNUM 50000
#define OUTF 128
#define NEDGE 1600000
#define EPSF 1e-7f

#define CONV_BLOCKS 6250    // 50000*128 / (256*4)
#define BFRAG_BLOCKS 64     // 16384 uint pairs / 256

#define CHUNK 2048          // edges per coarse/hist block
#define NCB 49              // coarse bins: tidx>>10 (1024 vertices/bin)
#define COARSE_BLOCKS 782   // ceil(NEDGE/CHUNK)

typedef __attribute__((ext_vector_type(8))) short short8;
typedef __attribute__((ext_vector_type(4))) float v4f;

// ---------------------------------------------------------------------------
// bf16 helpers (RNE)
// ---------------------------------------------------------------------------
__device__ __forceinline__ unsigned short f2bf(float f) {
    union { float f; unsigned int u; } c; c.f = f;
    unsigned int u = c.u;
    return (unsigned short)((u + 0x7FFFu + ((u >> 16) & 1u)) >> 16);
}
__device__ __forceinline__ float bf16_lo(unsigned int p) {
    union { unsigned int u; float f; } c; c.u = p << 16; return c.f;
}
__device__ __forceinline__ float bf16_hi(unsigned int p) {
    union { unsigned int u; float f; } c; c.u = p & 0xFFFF0000u; return c.f;
}

__device__ __forceinline__ int wave_incl_scan(int v, int lane) {
#pragma unroll
    for (int off = 1; off < 64; off <<= 1) {
        const int o = __shfl_up(v, off, 64);
        if (lane >= off) v += o;
    }
    return v;
}

// ---------------------------------------------------------------------------
// prep: (a) vrepr f32 -> packed bf16x2, (b) 49-bin coarse hist (LDS-staged),
// (c) MFMA B-fragment build.
// ---------------------------------------------------------------------------
__global__ __launch_bounds__(256) void prep_kernel(
    const float* __restrict__ vrepr, unsigned int* __restrict__ vrepr16,
    const int* __restrict__ tidx, int* __restrict__ chist,
    const float* __restrict__ loc_w, const float* __restrict__ std_w,
    unsigned int* bfrag)
{
    __shared__ int lc[4][NCB];
    const int b = blockIdx.x, tid = threadIdx.x;
    if (b < CONV_BLOCKS) {
        const size_t base = (size_t)b * 1024 + tid * 4;
        const float4 v = *reinterpret_cast<const float4*>(vrepr + base);
        uint2 o;
        o.x = (unsigned)f2bf(v.x) | ((unsigned)f2bf(v.y) << 16);
        o.y = (unsigned)f2bf(v.z) | ((unsigned)f2bf(v.w) << 16);
        *reinterpret_cast<uint2*>(vrepr16 + base / 2) = o;
    } else if (b < CONV_BLOCKS + COARSE_BLOCKS) {
        const int hb = b - CONV_BLOCKS;
        for (int i = tid; i < 4 * NCB; i += 256) (&lc[0][0])[i] = 0;
        __syncthreads();
        const int base = hb * CHUNK;
#pragma unroll
        for (int j = 0; j < 8; ++j) {
            const int e = base + j * 256 + tid;
            if (e < NEDGE) atomicAdd(&lc[tid >> 6][tidx[e] >> 10], 1);
        }
        __syncthreads();
        if (tid < NCB) {
            const int s = lc[0][tid] + lc[1][tid] + lc[2][tid] + lc[3][tid];
            if (s) atomicAdd(&chist[tid], s);
        }
    } else {
        const int p = (b - (CONV_BLOCKS + COARSE_BLOCKS)) * 256 + tid; // 0..16383
        const int j2 = p & 3, lq = (p >> 2) & 63, ks = (p >> 8) & 3, ct = p >> 10;
        const int k = ks * 32 + (lq >> 4) * 8 + j2 * 2;
        const int n = ct * 16 + (lq & 15);
        const float* wsrc = (n >> 7) ? std_w : loc_w;
        const int c = n & 127;
        bfrag[p] = (unsigned)f2bf(wsrc[c * 128 + k]) |
                   ((unsigned)f2bf(wsrc[c * 128 + k + 1]) << 16);
    }
}

// ---------------------------------------------------------------------------
// scan_coarse: single wave scans 49 bin counts -> cbase[50] + ccursor;
// seeds offs[VNUM] = NEDGE.
// ---------------------------------------------------------------------------
__global__ __launch_bounds__(64) void scan_coarse_kernel(
    const int* __restrict__ chist, int* __restrict__ cbase,
    int* __restrict__ ccursor, int* __restrict__ offs)
{
    const int tid = threadIdx.x;
    const int v = (tid < NCB) ? chist[tid] : 0;
    const int inc = wave_incl_scan(v, tid);
    const int ex = inc - v;
    if (tid < NCB) { cbase[tid] = ex; ccursor[tid] = ex; }
    if (tid == NCB - 1) { cbase[NCB] = inc; offs[VNUM] = inc; }  // == NEDGE
}

// ---------------------------------------------------------------------------
// coarse: partition edges into 49 bin segments via LDS staging + bulk-
// reserved contiguous runs. rec = { sidx<<16 | bf16(w), tidx }
// ---------------------------------------------------------------------------
__global__ __launch_bounds__(256) void coarse_kernel(
    const int* __restrict__ sidx, const int* __restrict__ tidx,
    const float* __restrict__ enorm, const float* __restrict__ esgn,
    int* __restrict__ ccursor, uint2* __restrict__ coarse8)
{
    __shared__ uint2 lrec[CHUNK];      // 16 KB
    __shared__ int lcnt[4][NCB];
    __shared__ int lbase[4][NCB];
    __shared__ int loffs[NCB];
    __shared__ int grun[NCB];

    const int tid = threadIdx.x, lane = tid & 63, wv = tid >> 6;
    const int base = blockIdx.x * CHUNK;
    const int n = min(CHUNK, NEDGE - base);

    for (int i = tid; i < 4 * NCB; i += 256) (&lcnt[0][0])[i] = 0;
    __syncthreads();

    uint2 rec[8];
#pragma unroll
    for (int j = 0; j < 8; ++j) {
        const int e = base + j * 256 + tid;
        if (e < NEDGE) {
            const int t = tidx[e];
            const float w = esgn[e] * enorm[e];
            rec[j].x = ((unsigned)sidx[e] << 16) | (unsigned)f2bf(w);
            rec[j].y = (unsigned)t;
            atomicAdd(&lcnt[wv][t >> 10], 1);
        }
    }
    __syncthreads();

    if (tid < 64) {
        int c0 = 0, c1 = 0, c2 = 0, c3 = 0, tot = 0;
        if (lane < NCB) {
            c0 = lcnt[0][lane]; c1 = lcnt[1][lane];
            c2 = lcnt[2][lane]; c3 = lcnt[3][lane];
            tot = c0 + c1 + c2 + c3;
        }
        const int inc = wave_incl_scan(tot, lane);
        const int ex = inc - tot;
        if (lane < NCB) {
            loffs[lane]    = ex;
            lbase[0][lane] = ex;
            lbase[1][lane] = ex + c0;
            lbase[2][lane] = ex + c0 + c1;
            lbase[3][lane] = ex + c0 + c1 + c2;
            grun[lane] = atomicAdd(&ccursor[lane], tot);
        }
    }
    __syncthreads();

#pragma unroll
    for (int j = 0; j < 8; ++j) {
        const int e = base + j * 256 + tid;
        if (e < NEDGE) {
            const int cb = (int)(rec[j].y >> 10);
            const int pos = atomicAdd(&lbase[wv][cb], 1);
            lrec[pos] = rec[j];
        }
    }
    __syncthreads();

    for (int i = tid; i < n; i += 256) {
        const uint2 r = lrec[i];
        const int cb = (int)(r.y >> 10);
        coarse8[grun[cb] + (i - loffs[cb])] = r;
    }
}

// ---------------------------------------------------------------------------
// binsort: fused binhist + scan + fine. One 1024-thread block per bin; the
// bin's ~261 KB record window is L2-resident so two passes are cheap.
// Pass 1: LDS hist of localt. Scan 1024 counters in-block -> offs + cursors.
// Pass 2: scatter payloads to exact CSR positions (LDS int atomics).
// ---------------------------------------------------------------------------
__global__ __launch_bounds__(1024) void binsort_kernel(
    const uint2* __restrict__ coarse8, const int* __restrict__ cbase,
    int* __restrict__ offs, unsigned int* __restrict__ pairs)
{
    __shared__ int cnt[1024];
    __shared__ int cur[1024];
    __shared__ int wsum[16];
    const int tid = threadIdx.x, lane = tid & 63, wv = tid >> 6;
    const int bin = blockIdx.x;
    const int s0 = cbase[bin], e0 = cbase[bin + 1];

    cnt[tid] = 0;
    __syncthreads();
    for (int i = s0 + tid; i < e0; i += 1024)
        atomicAdd(&cnt[coarse8[i].y & 1023], 1);
    __syncthreads();

    const int v = cnt[tid];
    const int inc = wave_incl_scan(v, lane);
    if (lane == 63) wsum[wv] = inc;
    __syncthreads();
    if (tid == 0) {
        int run = 0;
        for (int i2 = 0; i2 < 16; ++i2) { const int t2 = wsum[i2]; wsum[i2] = run; run += t2; }
    }
    __syncthreads();
    const int ex = s0 + wsum[wv] + inc - v;   // exclusive prefix + bin base
    const int gv = (bin << 10) + tid;
    if (gv < VNUM) offs[gv] = ex;
    cur[tid] = ex;
    __syncthreads();

    for (int i = s0 + tid; i < e0; i += 1024) {
        const uint2 r = coarse8[i];
        const int pos = atomicAdd(&cur[r.y & 1023], 1);
        pairs[pos] = r.x;
    }
}

// ---------------------------------------------------------------------------
// aggemm (fused aggregate + MFMA gemm): block = 16 vertices. Wave w
// aggregates vertices w*4..w*4+3 (lane covers cols 2l,2l+1), writes bf16
// results straight into the MFMA A-tile in LDS — no acc round-trip.
// Then 16x16x32 bf16 MFMA against preloaded B-frags, bias+softplus epilogue.
// ---------------------------------------------------------------------------
__global__ __launch_bounds__(256) void aggemm_kernel(
    const int* __restrict__ offs, const unsigned int* __restrict__ pairs,
    const unsigned int* __restrict__ vrepr16,
    const unsigned int* __restrict__ bfrag,
    const float* __restrict__ loc_b, const float* __restrict__ std_b,
    float* out)
{
    __shared__ unsigned short tile[16][136];   // bf16 A-tile, padded
    const int t = threadIdx.x, l = t & 63, w = t >> 6;
    const int row0 = blockIdx.x * 16;

#pragma unroll
    for (int r = 0; r < 4; ++r) {
        const int vtx = row0 + w * 4 + r;
        int i = offs[vtx];
        const int end = offs[vtx + 1];
        float a0 = 0.0f, a1 = 0.0f;
        for (; i + 4 <= end; i += 4) {
            const unsigned p0 = pairs[i], p1 = pairs[i + 1];
            const unsigned p2 = pairs[i + 2], p3 = pairs[i + 3];
            const unsigned r0 = vrepr16[(size_t)(p0 >> 16) * 64 + l];
            const unsigned r1 = vrepr16[(size_t)(p1 >> 16) * 64 + l];
            const unsigned r2 = vrepr16[(size_t)(p2 >> 16) * 64 + l];
            const unsigned r3 = vrepr16[(size_t)(p3 >> 16) * 64 + l];
            const float w0 = bf16_lo(p0), w1 = bf16_lo(p1);
            const float w2 = bf16_lo(p2), w3 = bf16_lo(p3);
            a0 = fmaf(bf16_lo(r0), w0, a0); a1 = fmaf(bf16_hi(r0), w0, a1);
            a0 = fmaf(bf16_lo(r1), w1, a0); a1 = fmaf(bf16_hi(r1), w1, a1);
            a0 = fmaf(bf16_lo(r2), w2, a0); a1 = fmaf(bf16_hi(r2), w2, a1);
            a0 = fmaf(bf16_lo(r3), w3, a0); a1 = fmaf(bf16_hi(r3), w3, a1);
        }
        for (; i < end; ++i) {
            const unsigned p = pairs[i];
            const unsigned rr = vrepr16[(size_t)(p >> 16) * 64 + l];
            const float ww = bf16_lo(p);
            a0 = fmaf(bf16_lo(rr), ww, a0); a1 = fmaf(bf16_hi(rr), ww, a1);
        }
        const unsigned pk = (unsigned)f2bf(a0) | ((unsigned)f2bf(a1) << 16);
        *reinterpret_cast<unsigned*>(&tile[w * 4 + r][2 * l]) = pk;
    }

    // preload B fragments (L2-resident)
    short8 bfr[4][4];
#pragma unroll
    for (int ct = 0; ct < 4; ++ct)
#pragma unroll
        for (int ks = 0; ks < 4; ++ks)
            bfr[ct][ks] = *reinterpret_cast<const short8*>(
                bfrag + ((((w * 4 + ct) * 4 + ks) * 64 + l) << 2));
    __syncthreads();

    const int m = l & 15, q = l >> 4;
    v4f accv[4];
#pragma unroll
    for (int ct = 0; ct < 4; ++ct) accv[ct] = (v4f){0.0f, 0.0f, 0.0f, 0.0f};

#pragma unroll
    for (int ks = 0; ks < 4; ++ks) {
        const short8 a = *reinterpret_cast<const short8*>(&tile[m][ks * 32 + q * 8]);
#pragma unroll
        for (int ct = 0; ct < 4; ++ct)
            accv[ct] = __builtin_amdgcn_mfma_f32_16x16x32_bf16(
                a, bfr[ct][ks], accv[ct], 0, 0, 0);
    }

#pragma unroll
    for (int ct = 0; ct < 4; ++ct) {
        const int colg = (w * 4 + ct) * 16 + m;
        const int h = colg >> 7, c = colg & 127;
        const float bias = (h ? std_b : loc_b)[c];
        float* dst = out + (h ? (size_t)VNUM * OUTF : (size_t)0);
#pragma unroll
        for (int reg = 0; reg < 4; ++reg) {
            const int row = row0 + q * 4 + reg;
            float x = accv[ct][reg] + bias;
            if (h) x = fmaxf(x, 0.0f) + log1pf(expf(-fabsf(x))) + EPSF;
            dst[(size_t)row * OUTF + c] = x;
        }
    }
}

// ---------------------------------------------------------------------------
// Fallback split path (ws < 20 MB): R8-proven aggregate + gemm_mfma.
// ---------------------------------------------------------------------------
__global__ __launch_bounds__(256) void aggregate_kernel(
    const int* __restrict__ offs, const unsigned int* __restrict__ pairs,
    const unsigned int* __restrict__ vrepr16, float* __restrict__ acc)
{
    const int v = blockIdx.x * 4 + (threadIdx.x >> 6);
    const int l = threadIdx.x & 63;
    int i = offs[v];
    const int end = offs[v + 1];

    float a0 = 0.0f, a1 = 0.0f;
    for (; i + 4 <= end; i += 4) {
        const unsigned p0 = pairs[i], p1 = pairs[i + 1];
        const unsigned p2 = pairs[i + 2], p3 = pairs[i + 3];
        const unsigned r0 = vrepr16[(size_t)(p0 >> 16) * 64 + l];
        const unsigned r1 = vrepr16[(size_t)(p1 >> 16) * 64 + l];
        const unsigned r2 = vrepr16[(size_t)(p2 >> 16) * 64 + l];
        const unsigned r3 = vrepr16[(size_t)(p3 >> 16) * 64 + l];
        const float w0 = bf16_lo(p0), w1 = bf16_lo(p1);
        const float w2 = bf16_lo(p2), w3 = bf16_lo(p3);
        a0 = fmaf(bf16_lo(r0), w0, a0); a1 = fmaf(bf16_hi(r0), w0, a1);
        a0 = fmaf(bf16_lo(r1), w1, a0); a1 = fmaf(bf16_hi(r1), w1, a1);
        a0 = fmaf(bf16_lo(r2), w2, a0); a1 = fmaf(bf16_hi(r2), w2, a1);
        a0 = fmaf(bf16_lo(r3), w3, a0); a1 = fmaf(bf16_hi(r3), w3, a1);
    }
    for (; i < end; ++i) {
        const unsigned p = pairs[i];
        const unsigned r = vrepr16[(size_t)(p >> 16) * 64 + l];
        const float w = bf16_lo(p);
        a0 = fmaf(bf16_lo(r), w, a0); a1 = fmaf(bf16_hi(r), w, a1);
    }
    *reinterpret_cast<float2*>(acc + (size_t)v * OUTF + 2 * l) = make_float2(a0, a1);
}

__global__ __launch_bounds__(256) void gemm_mfma_kernel(
    const float* acc, const unsigned int* __restrict__ bfrag,
    const float* __restrict__ loc_b, const float* __restrict__ std_b,
    float* out)
{
    __shared__ unsigned short tile[16][136];
    const int t = threadIdx.x;
    const int row0 = blockIdx.x * 16;
    const int l = t & 63, w = t >> 6;

    short8 bfr[4][4];
#pragma unroll
    for (int ct = 0; ct < 4; ++ct)
#pragma unroll
        for (int ks = 0; ks < 4; ++ks)
            bfr[ct][ks] = *reinterpret_cast<const short8*>(
                bfrag + ((((w * 4 + ct) * 4 + ks) * 64 + l) << 2));

    {
        const float* src = acc + (size_t)row0 * OUTF + t * 8;
        const float4 v0 = *reinterpret_cast<const float4*>(src);
        const float4 v1 = *reinterpret_cast<const float4*>(src + 4);
        uint4 pk;
        pk.x = (unsigned)f2bf(v0.x) | ((unsigned)f2bf(v0.y) << 16);
        pk.y = (unsigned)f2bf(v0.z) | ((unsigned)f2bf(v0.w) << 16);
        pk.z = (unsigned)f2bf(v1.x) | ((unsigned)f2bf(v1.y) << 16);
        pk.w = (unsigned)f2bf(v1.z) | ((unsigned)f2bf(v1.w) << 16);
        *reinterpret_cast<uint4*>(&tile[t >> 4][(t & 15) * 8]) = pk;
    }
    __syncthreads();

    const int m = l & 15, q = l >> 4;
    v4f accv[4];
#pragma unroll
    for (int ct = 0; ct < 4; ++ct) accv[ct] = (v4f){0.0f, 0.0f, 0.0f, 0.0f};

#pragma unroll
    for (int ks = 0; ks < 4; ++ks) {
        const short8 a = *reinterpret_cast<const short8*>(&tile[m][ks * 32 + q * 8]);
#pragma unroll
        for (int ct = 0; ct < 4; ++ct)
            accv[ct] = __builtin_amdgcn_mfma_f32_16x16x32_bf16(
                a, bfr[ct][ks], accv[ct], 0, 0, 0);
    }

#pragma unroll
    for (int ct = 0; ct < 4; ++ct) {
        const int colg = (w * 4 + ct) * 16 + m;
        const int h = colg >> 7, c = colg & 127;
        const float bias = (h ? std_b : loc_b)[c];
        float* dst = out + (h ? (size_t)VNUM * OUTF : (size_t)0);
#pragma unroll
        for (int reg = 0; reg < 4; ++reg) {
            const int row = row0 + q * 4 + reg;
            float x = accv[ct][reg] + bias;
            if (h) x = fmaxf(x, 0.0f) + log1pf(expf(-fabsf(x))) + EPSF;
            dst[(size_t)row * OUTF + c] = x;
        }
    }
}

extern "C" void kernel_launch(void* const* d_in, const int* in_sizes, int n_in,
                              void* d_out, int out_size, void* d_ws, size_t ws_size,
                              hipStream_t stream) {
    const int*   sidx  = (const int*)  d_in[0];
    const int*   tidx  = (const int*)  d_in[1];
    const float* enorm = (const float*)d_in[2];
    const float* esgn  = (const float*)d_in[3];
    const float* vrepr = (const float*)d_in[4];
    const float* loc_w = (const float*)d_in[5];
    const float* loc_b = (const float*)d_in[6];
    const float* std_w = (const float*)d_in[7];
    const float* std_b = (const float*)d_in[8];

    float* out = (float*)d_out;

    // coarse8 (12.8 MB) borrows the loc half of out; dead before outputs write.
    uint2* coarse8 = (uint2*)out;

    // std-half small scratch (pre-output phase only): cbase/ccursor/chist
    unsigned int* sbase = (unsigned int*)(out + (size_t)VNUM * OUTF);
    // fused path needs pairs/vrepr16/offs OUT of the output buffer (the fused
    // kernel writes outputs while reading them) -> workspace when big enough.
    const size_t WS_WORDS_NEED = 16384 + (VNUM + 1) + NEDGE + (size_t)VNUM * 64;
    const bool fused = ws_size >= WS_WORDS_NEED * sizeof(unsigned int);

    unsigned int* bfrag;
    int* offs;
    unsigned int* pairs;
    unsigned int* vrepr16;
    int *cbase, *ccursor, *chist;

    if (fused) {
        unsigned int* wsb = (unsigned int*)d_ws;
        bfrag   = wsb;
        offs    = (int*)(wsb + 16384);
        pairs   = wsb + 16384 + (VNUM + 1);
        vrepr16 = pairs + NEDGE;
        cbase   = (int*)sbase;
        ccursor = cbase + NCB + 1;
        chist   = ccursor + NCB;
    } else {
        // R8 layout: everything in the std half (safe: aggregate/gemm split)
        pairs   = sbase;
        vrepr16 = sbase + NEDGE;
        offs    = (int*)(sbase + NEDGE + (size_t)VNUM * 64);
        cbase   = offs + VNUM + 1;
        ccursor = cbase + NCB + 1;
        chist   = ccursor + NCB;
        bfrag   = (unsigned int*)d_ws;   // >=64 KB (bench-confirmed >=128 KB)
    }

    hipMemsetAsync(chist, 0, NCB * sizeof(int), stream);

    const int prep_blocks = CONV_BLOCKS + COARSE_BLOCKS + BFRAG_BLOCKS;
    prep_kernel       <<<prep_blocks, 256, 0, stream>>>(vrepr, vrepr16, tidx, chist,
                                                        loc_w, std_w, bfrag);
    scan_coarse_kernel<<<1, 64, 0, stream>>>(chist, cbase, ccursor, offs);
    coarse_kernel     <<<COARSE_BLOCKS, 256, 0, stream>>>(sidx, tidx, enorm, esgn,
                                                          ccursor, coarse8);
    binsort_kernel    <<<NCB, 1024, 0, stream>>>(coarse8, cbase, offs, pairs);

    if (fused) {
        aggemm_kernel<<<VNUM / 16, 256, 0, stream>>>(offs, pairs, vrepr16, bfrag,
                                                     loc_b, std_b, out);
    } else {
        float* acc = out;   // loc half (coarse8 dead after binsort)
        aggregate_kernel<<<VNUM / 4, 256, 0, stream>>>(offs, pairs, vrepr16, acc);
        gemm_mfma_kernel<<<VNUM / 16, 256, 0, stream>>>(acc, bfrag, loc_b, std_b, out);
    }
}

// Round 10
// 266.663 us; speedup vs baseline: 1.1417x; 1.1417x over previous
//
#include <hip/hip_runtime.h>
#include <math.h>

#define VNUM 50000
#define OUTF 128
#define NEDGE 1600000
#define EPSF 1e-7f

#define CONV_BLOCKS 6250    // 50000*128 / (256*4)
#define BFRAG_BLOCKS 64     // 16384 uint pairs / 256

#define CHUNK 2048          // edges per coarse/hist block
#define NCB 49              // coarse bins: tidx>>10 (1024 vertices/bin)
#define COARSE_BLOCKS 782   // ceil(NEDGE/CHUNK)

typedef __attribute__((ext_vector_type(8))) short short8;
typedef __attribute__((ext_vector_type(4))) float v4f;

// ---------------------------------------------------------------------------
// bf16 helpers (RNE)
// ---------------------------------------------------------------------------
__device__ __forceinline__ unsigned short f2bf(float f) {
    union { float f; unsigned int u; } c; c.f = f;
    unsigned int u = c.u;
    return (unsigned short)((u + 0x7FFFu + ((u >> 16) & 1u)) >> 16);
}
__device__ __forceinline__ float bf16_lo(unsigned int p) {
    union { unsigned int u; float f; } c; c.u = p << 16; return c.f;
}
__device__ __forceinline__ float bf16_hi(unsigned int p) {
    union { unsigned int u; float f; } c; c.u = p & 0xFFFF0000u; return c.f;
}

__device__ __forceinline__ int wave_incl_scan(int v, int lane) {
#pragma unroll
    for (int off = 1; off < 64; off <<= 1) {
        const int o = __shfl_up(v, off, 64);
        if (lane >= off) v += o;
    }
    return v;
}

// ---------------------------------------------------------------------------
// prep: (a) vrepr f32 -> packed bf16x2, (b) 49-bin coarse hist (LDS-staged),
// (c) MFMA B-fragment build into d_ws.
// ---------------------------------------------------------------------------
__global__ __launch_bounds__(256) void prep_kernel(
    const float* __restrict__ vrepr, unsigned int* __restrict__ vrepr16,
    const int* __restrict__ tidx, int* __restrict__ chist,
    const float* __restrict__ loc_w, const float* __restrict__ std_w,
    unsigned int* bfrag)
{
    __shared__ int lc[4][NCB];
    const int b = blockIdx.x, tid = threadIdx.x;
    if (b < CONV_BLOCKS) {
        const size_t base = (size_t)b * 1024 + tid * 4;
        const float4 v = *reinterpret_cast<const float4*>(vrepr + base);
        uint2 o;
        o.x = (unsigned)f2bf(v.x) | ((unsigned)f2bf(v.y) << 16);
        o.y = (unsigned)f2bf(v.z) | ((unsigned)f2bf(v.w) << 16);
        *reinterpret_cast<uint2*>(vrepr16 + base / 2) = o;
    } else if (b < CONV_BLOCKS + COARSE_BLOCKS) {
        const int hb = b - CONV_BLOCKS;
        for (int i = tid; i < 4 * NCB; i += 256) (&lc[0][0])[i] = 0;
        __syncthreads();
        const int base = hb * CHUNK;
#pragma unroll
        for (int j = 0; j < 8; ++j) {
            const int e = base + j * 256 + tid;
            if (e < NEDGE) atomicAdd(&lc[tid >> 6][tidx[e] >> 10], 1);
        }
        __syncthreads();
        if (tid < NCB) {
            const int s = lc[0][tid] + lc[1][tid] + lc[2][tid] + lc[3][tid];
            if (s) atomicAdd(&chist[tid], s);
        }
    } else {
        const int p = (b - (CONV_BLOCKS + COARSE_BLOCKS)) * 256 + tid; // 0..16383
        const int j2 = p & 3, lq = (p >> 2) & 63, ks = (p >> 8) & 3, ct = p >> 10;
        const int k = ks * 32 + (lq >> 4) * 8 + j2 * 2;
        const int n = ct * 16 + (lq & 15);
        const float* wsrc = (n >> 7) ? std_w : loc_w;
        const int c = n & 127;
        bfrag[p] = (unsigned)f2bf(wsrc[c * 128 + k]) |
                   ((unsigned)f2bf(wsrc[c * 128 + k + 1]) << 16);
    }
}

// ---------------------------------------------------------------------------
// scan_coarse: single wave scans 49 bin counts -> cbase[50] + ccursor;
// seeds offs[VNUM] = NEDGE.
// ---------------------------------------------------------------------------
__global__ __launch_bounds__(64) void scan_coarse_kernel(
    const int* __restrict__ chist, int* __restrict__ cbase,
    int* __restrict__ ccursor, int* __restrict__ offs)
{
    const int tid = threadIdx.x;
    const int v = (tid < NCB) ? chist[tid] : 0;
    const int inc = wave_incl_scan(v, tid);
    const int ex = inc - v;
    if (tid < NCB) { cbase[tid] = ex; ccursor[tid] = ex; }
    if (tid == NCB - 1) { cbase[NCB] = inc; offs[VNUM] = inc; }  // == NEDGE
}

// ---------------------------------------------------------------------------
// coarse: partition edges into 49 bin segments via LDS staging + bulk-
// reserved contiguous runs. rec = { sidx<<16 | bf16(w), tidx }
// ---------------------------------------------------------------------------
__global__ __launch_bounds__(256) void coarse_kernel(
    const int* __restrict__ sidx, const int* __restrict__ tidx,
    const float* __restrict__ enorm, const float* __restrict__ esgn,
    int* __restrict__ ccursor, uint2* __restrict__ coarse8)
{
    __shared__ uint2 lrec[CHUNK];      // 16 KB
    __shared__ int lcnt[4][NCB];
    __shared__ int lbase[4][NCB];
    __shared__ int loffs[NCB];
    __shared__ int grun[NCB];

    const int tid = threadIdx.x, lane = tid & 63, wv = tid >> 6;
    const int base = blockIdx.x * CHUNK;
    const int n = min(CHUNK, NEDGE - base);

    for (int i = tid; i < 4 * NCB; i += 256) (&lcnt[0][0])[i] = 0;
    __syncthreads();

    uint2 rec[8];
#pragma unroll
    for (int j = 0; j < 8; ++j) {
        const int e = base + j * 256 + tid;
        if (e < NEDGE) {
            const int t = tidx[e];
            const float w = esgn[e] * enorm[e];
            rec[j].x = ((unsigned)sidx[e] << 16) | (unsigned)f2bf(w);
            rec[j].y = (unsigned)t;
            atomicAdd(&lcnt[wv][t >> 10], 1);
        }
    }
    __syncthreads();

    if (tid < 64) {
        int c0 = 0, c1 = 0, c2 = 0, c3 = 0, tot = 0;
        if (lane < NCB) {
            c0 = lcnt[0][lane]; c1 = lcnt[1][lane];
            c2 = lcnt[2][lane]; c3 = lcnt[3][lane];
            tot = c0 + c1 + c2 + c3;
        }
        const int inc = wave_incl_scan(tot, lane);
        const int ex = inc - tot;
        if (lane < NCB) {
            loffs[lane]    = ex;
            lbase[0][lane] = ex;
            lbase[1][lane] = ex + c0;
            lbase[2][lane] = ex + c0 + c1;
            lbase[3][lane] = ex + c0 + c1 + c2;
            grun[lane] = atomicAdd(&ccursor[lane], tot);
        }
    }
    __syncthreads();

#pragma unroll
    for (int j = 0; j < 8; ++j) {
        const int e = base + j * 256 + tid;
        if (e < NEDGE) {
            const int cb = (int)(rec[j].y >> 10);
            const int pos = atomicAdd(&lbase[wv][cb], 1);
            lrec[pos] = rec[j];
        }
    }
    __syncthreads();

    for (int i = tid; i < n; i += 256) {
        const uint2 r = lrec[i];
        const int cb = (int)(r.y >> 10);
        coarse8[grun[cb] + (i - loffs[cb])] = r;
    }
}

// ---------------------------------------------------------------------------
// binsort (R9-proven win): fused binhist + scan + fine. One 1024-thread
// block per bin; the bin's ~261 KB record window is L2-resident.
// ---------------------------------------------------------------------------
__global__ __launch_bounds__(1024) void binsort_kernel(
    const uint2* __restrict__ coarse8, const int* __restrict__ cbase,
    int* __restrict__ offs, unsigned int* __restrict__ pairs)
{
    __shared__ int cnt[1024];
    __shared__ int cur[1024];
    __shared__ int wsum[16];
    const int tid = threadIdx.x, lane = tid & 63, wv = tid >> 6;
    const int bin = blockIdx.x;
    const int s0 = cbase[bin], e0 = cbase[bin + 1];

    cnt[tid] = 0;
    __syncthreads();
    for (int i = s0 + tid; i < e0; i += 1024)
        atomicAdd(&cnt[coarse8[i].y & 1023], 1);
    __syncthreads();

    const int v = cnt[tid];
    const int inc = wave_incl_scan(v, lane);
    if (lane == 63) wsum[wv] = inc;
    __syncthreads();
    if (tid == 0) {
        int run = 0;
        for (int i2 = 0; i2 < 16; ++i2) { const int t2 = wsum[i2]; wsum[i2] = run; run += t2; }
    }
    __syncthreads();
    const int ex = s0 + wsum[wv] + inc - v;   // exclusive prefix + bin base
    const int gv = (bin << 10) + tid;
    if (gv < VNUM) offs[gv] = ex;
    cur[tid] = ex;
    __syncthreads();

    for (int i = s0 + tid; i < e0; i += 1024) {
        const uint2 r = coarse8[i];
        const int pos = atomicAdd(&cur[r.y & 1023], 1);
        pairs[pos] = r.x;
    }
}

// ---------------------------------------------------------------------------
// aggregate: one wave per vertex, lane covers cols (2l, 2l+1). 256 B
// coalesced bf16-row gathers, unroll-8 for MLP, float2 store.
// ---------------------------------------------------------------------------
__global__ __launch_bounds__(256) void aggregate_kernel(
    const int* __restrict__ offs, const unsigned int* __restrict__ pairs,
    const unsigned int* __restrict__ vrepr16, float* __restrict__ acc)
{
    const int v = blockIdx.x * 4 + (threadIdx.x >> 6);
    const int l = threadIdx.x & 63;
    int i = offs[v];
    const int end = offs[v + 1];

    float a0 = 0.0f, a1 = 0.0f;
    for (; i + 8 <= end; i += 8) {
        unsigned p[8], r[8];
#pragma unroll
        for (int j = 0; j < 8; ++j) p[j] = pairs[i + j];
#pragma unroll
        for (int j = 0; j < 8; ++j) r[j] = vrepr16[(size_t)(p[j] >> 16) * 64 + l];
#pragma unroll
        for (int j = 0; j < 8; ++j) {
            const float w = bf16_lo(p[j]);
            a0 = fmaf(bf16_lo(r[j]), w, a0);
            a1 = fmaf(bf16_hi(r[j]), w, a1);
        }
    }
    for (; i + 4 <= end; i += 4) {
        const unsigned p0 = pairs[i], p1 = pairs[i + 1];
        const unsigned p2 = pairs[i + 2], p3 = pairs[i + 3];
        const unsigned r0 = vrepr16[(size_t)(p0 >> 16) * 64 + l];
        const unsigned r1 = vrepr16[(size_t)(p1 >> 16) * 64 + l];
        const unsigned r2 = vrepr16[(size_t)(p2 >> 16) * 64 + l];
        const unsigned r3 = vrepr16[(size_t)(p3 >> 16) * 64 + l];
        const float w0 = bf16_lo(p0), w1 = bf16_lo(p1);
        const float w2 = bf16_lo(p2), w3 = bf16_lo(p3);
        a0 = fmaf(bf16_lo(r0), w0, a0); a1 = fmaf(bf16_hi(r0), w0, a1);
        a0 = fmaf(bf16_lo(r1), w1, a0); a1 = fmaf(bf16_hi(r1), w1, a1);
        a0 = fmaf(bf16_lo(r2), w2, a0); a1 = fmaf(bf16_hi(r2), w2, a1);
        a0 = fmaf(bf16_lo(r3), w3, a0); a1 = fmaf(bf16_hi(r3), w3, a1);
    }
    for (; i < end; ++i) {
        const unsigned p = pairs[i];
        const unsigned r = vrepr16[(size_t)(p >> 16) * 64 + l];
        const float w = bf16_lo(p);
        a0 = fmaf(bf16_lo(r), w, a0); a1 = fmaf(bf16_hi(r), w, a1);
    }
    *reinterpret_cast<float2*>(acc + (size_t)v * OUTF + 2 * l) = make_float2(a0, a1);
}

// ---------------------------------------------------------------------------
// gemm via MFMA 16x16x32 bf16 (R7/R8-proven).
// ---------------------------------------------------------------------------
__global__ __launch_bounds__(256) void gemm_mfma_kernel(
    const float* acc, const unsigned int* __restrict__ bfrag,
    const float* __restrict__ loc_b, const float* __restrict__ std_b,
    float* out)
{
    __shared__ unsigned short tile[16][136];   // bf16, padded
    const int t = threadIdx.x;
    const int row0 = blockIdx.x * 16;
    const int l = t & 63, w = t >> 6;

    short8 bfr[4][4];
#pragma unroll
    for (int ct = 0; ct < 4; ++ct)
#pragma unroll
        for (int ks = 0; ks < 4; ++ks)
            bfr[ct][ks] = *reinterpret_cast<const short8*>(
                bfrag + ((((w * 4 + ct) * 4 + ks) * 64 + l) << 2));

    {
        const float* src = acc + (size_t)row0 * OUTF + t * 8;
        const float4 v0 = *reinterpret_cast<const float4*>(src);
        const float4 v1 = *reinterpret_cast<const float4*>(src + 4);
        uint4 pk;
        pk.x = (unsigned)f2bf(v0.x) | ((unsigned)f2bf(v0.y) << 16);
        pk.y = (unsigned)f2bf(v0.z) | ((unsigned)f2bf(v0.w) << 16);
        pk.z = (unsigned)f2bf(v1.x) | ((unsigned)f2bf(v1.y) << 16);
        pk.w = (unsigned)f2bf(v1.z) | ((unsigned)f2bf(v1.w) << 16);
        *reinterpret_cast<uint4*>(&tile[t >> 4][(t & 15) * 8]) = pk;
    }
    __syncthreads();

    const int m = l & 15, q = l >> 4;
    v4f accv[4];
#pragma unroll
    for (int ct = 0; ct < 4; ++ct) accv[ct] = (v4f){0.0f, 0.0f, 0.0f, 0.0f};

#pragma unroll
    for (int ks = 0; ks < 4; ++ks) {
        const short8 a = *reinterpret_cast<const short8*>(&tile[m][ks * 32 + q * 8]);
#pragma unroll
        for (int ct = 0; ct < 4; ++ct)
            accv[ct] = __builtin_amdgcn_mfma_f32_16x16x32_bf16(
                a, bfr[ct][ks], accv[ct], 0, 0, 0);
    }

#pragma unroll
    for (int ct = 0; ct < 4; ++ct) {
        const int colg = (w * 4 + ct) * 16 + m;
        const int h = colg >> 7, c = colg & 127;
        const float bias = (h ? std_b : loc_b)[c];
        float* dst = out + (h ? (size_t)VNUM * OUTF : (size_t)0);
#pragma unroll
        for (int reg = 0; reg < 4; ++reg) {
            const int row = row0 + q * 4 + reg;
            float x = accv[ct][reg] + bias;
            if (h) x = fmaxf(x, 0.0f) + log1pf(expf(-fabsf(x))) + EPSF;
            dst[(size_t)row * OUTF + c] = x;
        }
    }
}

// Fallback gemm (no workspace): f32 vector path.
__global__ __launch_bounds__(256) void gemm_fallback_kernel(
    const float* acc,
    const float* __restrict__ loc_w, const float* __restrict__ loc_b,
    const float* __restrict__ std_w, const float* __restrict__ std_b,
    float* out)
{
    __shared__ float tile[16][OUTF];
    const int t = threadIdx.x;
    const int row0 = blockIdx.x * 16;
    {
        const float4* src = reinterpret_cast<const float4*>(acc + (size_t)row0 * OUTF);
        float4* dst = reinterpret_cast<float4*>(&tile[0][0]);
        dst[t] = src[t]; dst[t + 256] = src[t + 256];
    }
    __syncthreads();
    const int is_std = t >> 7;
    const int c = t & 127;
    const float* w = (is_std ? std_w : loc_w) + (size_t)c * OUTF;
    const float bias = is_std ? std_b[c] : loc_b[c];
    float accv[16];
#pragma unroll
    for (int r = 0; r < 16; ++r) accv[r] = 0.0f;
    for (int k = 0; k < OUTF; k += 4) {
        const float4 wv = *reinterpret_cast<const float4*>(w + k);
#pragma unroll
        for (int r = 0; r < 16; ++r) {
            const float4 pv = *reinterpret_cast<const float4*>(&tile[r][k]);
            float a = accv[r];
            a = fmaf(pv.x, wv.x, a); a = fmaf(pv.y, wv.y, a);
            a = fmaf(pv.z, wv.z, a); a = fmaf(pv.w, wv.w, a);
            accv[r] = a;
        }
    }
    float* dst_base = out + (is_std ? (size_t)VNUM * OUTF : (size_t)0);
#pragma unroll
    for (int r = 0; r < 16; ++r) {
        const float x = accv[r] + bias;
        dst_base[(size_t)(row0 + r) * OUTF + c] =
            is_std ? (fmaxf(x, 0.0f) + log1pf(expf(-fabsf(x))) + EPSF) : x;
    }
}

extern "C" void kernel_launch(void* const* d_in, const int* in_sizes, int n_in,
                              void* d_out, int out_size, void* d_ws, size_t ws_size,
                              hipStream_t stream) {
    const int*   sidx  = (const int*)  d_in[0];
    const int*   tidx  = (const int*)  d_in[1];
    const float* enorm = (const float*)d_in[2];
    const float* esgn  = (const float*)d_in[3];
    const float* vrepr = (const float*)d_in[4];
    const float* loc_w = (const float*)d_in[5];
    const float* loc_b = (const float*)d_in[6];
    const float* std_w = (const float*)d_in[7];
    const float* std_b = (const float*)d_in[8];

    float* out = (float*)d_out;

    // coarse8 (12.8 MB) borrows the loc half of out; dead after binsort,
    // then the loc half becomes acc (segment sums).
    uint2* coarse8 = (uint2*)out;

    // std-half scratch (R8-proven layout):
    //   pairs 1.6M | vrepr16 3.2M | offs 50001 | cbase 50 | ccursor 49 |
    //   chist 49   (~4.85M of 6.4M words)
    unsigned int* sbase   = (unsigned int*)(out + (size_t)VNUM * OUTF);
    unsigned int* pairs   = sbase;
    unsigned int* vrepr16 = sbase + NEDGE;
    int* offs    = (int*)(sbase + NEDGE + (size_t)VNUM * 64);
    int* cbase   = offs + VNUM + 1;
    int* ccursor = cbase + NCB + 1;
    int* chist   = ccursor + NCB;

    const bool use_ws = ws_size >= 16384 * sizeof(unsigned int);  // 64 KB
    unsigned int* bfrag = use_ws ? (unsigned int*)d_ws : nullptr;

    hipMemsetAsync(chist, 0, NCB * sizeof(int), stream);

    const int prep_blocks = CONV_BLOCKS + COARSE_BLOCKS + (use_ws ? BFRAG_BLOCKS : 0);
    prep_kernel       <<<prep_blocks, 256, 0, stream>>>(vrepr, vrepr16, tidx, chist,
                                                        loc_w, std_w, bfrag);
    scan_coarse_kernel<<<1, 64, 0, stream>>>(chist, cbase, ccursor, offs);
    coarse_kernel     <<<COARSE_BLOCKS, 256, 0, stream>>>(sidx, tidx, enorm, esgn,
                                                          ccursor, coarse8);
    binsort_kernel    <<<NCB, 1024, 0, stream>>>(coarse8, cbase, offs, pairs);

    float* acc = out;   // loc half (coarse8 dead after binsort)
    aggregate_kernel<<<VNUM / 4, 256, 0, stream>>>(offs, pairs, vrepr16, acc);

    if (use_ws) {
        gemm_mfma_kernel<<<VNUM / 16, 256, 0, stream>>>(acc, bfrag, loc_b, std_b, out);
    } else {
        gemm_fallback_kernel<<<VNUM / 16, 256, 0, stream>>>(acc, loc_w, loc_b,
                                                            std_w, std_b, out);
    }
}